// Round 3
// baseline (876.437 us; speedup 1.0000x reference)
//
#include <hip/hip_runtime.h>

// ---------------------------------------------------------------------------
// BertAlibiUnpadSelfAttention on MI355X.
// MEASUREMENT ROUND (de-risked): attn kernel replicated 4x (grid 3072).
// ALL replicas compute identical results and all write d_out (identical-byte
// WAW race is benign; final bytes = correct bytes). No scratch usage, no
// OOB risk. Purpose: (a) dur_us delta = 3x attn duration, (b) the 4x attn
// dispatch exceeds the 245us fills and surfaces attn's own counters in top-5.
// K1/K2 byte-identical to round 1.
// ---------------------------------------------------------------------------

typedef __attribute__((ext_vector_type(8))) short short8;
typedef __attribute__((ext_vector_type(4))) float floatx4;
typedef unsigned short u16;
typedef unsigned int u32;

#define LOG2E 1.4426950408889634f

__device__ __forceinline__ u16 f2bf(float f) {
  u32 u = __float_as_uint(f);
  u += 0x7FFFu + ((u >> 16) & 1u);   // round-to-nearest-even
  return (u16)(u >> 16);
}

typedef const __attribute__((address_space(1))) u32* gp_t;
typedef __attribute__((address_space(3))) u32* lp_t;
__device__ __forceinline__ void async_cp16(const void* g, void* l) {
  __builtin_amdgcn_global_load_lds((gp_t)g, (lp_t)l, 16, 0, 0);
}

// ------------------------------- K1: pack ----------------------------------
__global__ __launch_bounds__(256) void pack_kernel(
    const float* __restrict__ A, const float* __restrict__ W,
    u16* __restrict__ Abf, u16* __restrict__ Wbf) {
  unsigned u = blockIdx.x * 256u + threadIdx.x;  // 1,228,800 float4 units
  const unsigned nA = 786432u;                   // 4096*768/4
  float4 v;
  u16* dst;
  if (u < nA) { v = ((const float4*)A)[u]; dst = Abf + u * 4; }
  else        { unsigned q = u - nA; v = ((const float4*)W)[q]; dst = Wbf + q * 4; }
  ushort4 o;
  o.x = f2bf(v.x); o.y = f2bf(v.y); o.z = f2bf(v.z); o.w = f2bf(v.w);
  *(ushort4*)dst = o;
}

// ------------------------------- K2: qkv gemm ------------------------------
// C[m,n] = sum_k Abf[m,k]*Wbf[n,k] + bq[n];  M=4096 N=2304 K=768
__global__ __launch_bounds__(256, 3) void qkv_gemm(
    const u16* __restrict__ Abf, const u16* __restrict__ Wbf,
    const float* __restrict__ bq,
    u16* __restrict__ Qb, u16* __restrict__ Kb, u16* __restrict__ Vb) {
  __shared__ __align__(16) char smem[32768];
  char* As0 = smem;
  char* Bs0 = smem + 8192;
  char* As1 = smem + 16384;
  char* Bs1 = smem + 24576;
  const unsigned t = threadIdx.x;
  unsigned orig = blockIdx.y * 18u + blockIdx.x;
  unsigned wg = (orig & 7u) * 72u + (orig >> 3);
  const unsigned nblk = wg % 18u, mblk = wg / 18u;
  const unsigned w = t >> 6, l = t & 63, quad = l >> 4, c = l & 15;
  const unsigned wm = (w >> 1) * 64, wn = (w & 1) * 64;

  floatx4 acc[4][4] = {};

  const unsigned b0 = t, b1 = t + 256u;
  const unsigned r0 = b0 >> 2, ch0 = (b0 & 3u) ^ (r0 & 3u);
  const unsigned r1 = b1 >> 2, ch1 = (b1 & 3u) ^ (r1 & 3u);
  const char* gA0 = (const char*)Abf + (size_t)((mblk * 128 + r0) * 768) * 2 + ch0 * 16;
  const char* gA1 = (const char*)Abf + (size_t)((mblk * 128 + r1) * 768) * 2 + ch1 * 16;
  const char* gB0 = (const char*)Wbf + (size_t)((nblk * 128 + r0) * 768) * 2 + ch0 * 16;
  const char* gB1 = (const char*)Wbf + (size_t)((nblk * 128 + r1) * 768) * 2 + ch1 * 16;

  async_cp16(gA0, As0 + b0 * 16);
  async_cp16(gA1, As0 + b1 * 16);
  async_cp16(gB0, Bs0 + b0 * 16);
  async_cp16(gB1, Bs0 + b1 * 16);
  __syncthreads();

  for (unsigned kt = 0; kt < 24; ++kt) {
    char* Ac = (kt & 1u) ? As1 : As0;
    char* Bc = (kt & 1u) ? Bs1 : Bs0;
    if (kt + 1 < 24) {
      char* An = (kt & 1u) ? As0 : As1;
      char* Bn = (kt & 1u) ? Bs0 : Bs1;
      async_cp16(gA0 + (kt + 1) * 64, An + b0 * 16);
      async_cp16(gA1 + (kt + 1) * 64, An + b1 * 16);
      async_cp16(gB0 + (kt + 1) * 64, Bn + b0 * 16);
      async_cp16(gB1 + (kt + 1) * 64, Bn + b1 * 16);
    }
    short8 af[4], bf[4];
#pragma unroll
    for (int mt = 0; mt < 4; ++mt) {
      unsigned row = wm + mt * 16 + c;
      af[mt] = *(const short8*)(Ac + row * 64 + 16 * (quad ^ (row & 3u)));
    }
#pragma unroll
    for (int nt = 0; nt < 4; ++nt) {
      unsigned row = wn + nt * 16 + c;
      bf[nt] = *(const short8*)(Bc + row * 64 + 16 * (quad ^ (row & 3u)));
    }
#pragma unroll
    for (int mt = 0; mt < 4; ++mt)
#pragma unroll
      for (int nt = 0; nt < 4; ++nt)
        acc[mt][nt] = __builtin_amdgcn_mfma_f32_16x16x32_bf16(af[mt], bf[nt], acc[mt][nt], 0, 0, 0);
    __syncthreads();
  }

  float bqv[4];
#pragma unroll
  for (int nt = 0; nt < 4; ++nt) bqv[nt] = bq[nblk * 128 + wn + nt * 16 + c];
#pragma unroll
  for (int mt = 0; mt < 4; ++mt) {
#pragma unroll
    for (int r = 0; r < 4; ++r) {
      unsigned m = mblk * 128 + wm + mt * 16 + quad * 4 + r;
      unsigned bb = m >> 11, s = m & 2047u;
#pragma unroll
      for (int nt = 0; nt < 4; ++nt) {
        float val = acc[mt][nt][r] + bqv[nt];
        unsigned n = nblk * 128 + wn + nt * 16 + c;
        u16 bv = f2bf(val);
        if (n < 768u) {
          unsigned h = n >> 6, d = n & 63u;
          Qb[(((bb * 12 + h) * 2048 + s) << 6) + d] = bv;
        } else if (n < 1536u) {
          unsigned n2 = n - 768u, h = n2 >> 6, d = n2 & 63u;
          Kb[(((bb * 12 + h) * 2048 + s) << 6) + d] = bv;
        } else {
          unsigned n2 = n - 1536u, h = n2 >> 6, d = n2 & 63u;
          Vb[(((bb * 12 + h) << 6) + d) * 2048 + s] = bv;
        }
      }
    }
  }
}

// ------------------------------- K3: attention -----------------------------
// grid = 3072 = 4 x 768. bx = bid % 768 (XCD-swizzled as before). All four
// replicas compute identical values and all write d_out (benign WAW).
__global__ __launch_bounds__(256, 3) void attn_kernel(
    const u16* __restrict__ Qb, const u16* __restrict__ Kb,
    const u16* __restrict__ Vb, const float* __restrict__ bias,
    float* __restrict__ out) {
  __shared__ __align__(16) char smem[49152];
  char* Qs  = smem;
  char* Ks0 = smem + 8192;
  char* Ks1 = smem + 16384;
  char* Vs0 = smem + 24576;
  char* Vs1 = smem + 32768;
  char* Ps  = smem + 40960;
  const unsigned t = threadIdx.x;
  const unsigned bx = blockIdx.x % 768u;   // replica id (bid/768) unused: all write out
  unsigned wgid = (bx & 7u) * 96u + (bx >> 3);
  const unsigned bh = wgid >> 5, qt = wgid & 31u;
  const unsigned q0 = qt * 64;
  const unsigned w = t >> 6, l = t & 63, quad = l >> 4, c = l & 15;

  const unsigned b0 = t, b1 = t + 256u;
  const unsigned r0 = b0 >> 3, ch0 = (b0 & 7u) ^ (r0 & 7u);
  const unsigned r1 = b1 >> 3, ch1 = (b1 & 7u) ^ (r1 & 7u);

  const char* gK0 = (const char*)Kb + (size_t)(bh * 2048 + r0) * 128 + ch0 * 16;
  const char* gK1 = (const char*)Kb + (size_t)(bh * 2048 + r1) * 128 + ch1 * 16;
  const char* gV0 = (const char*)Vb + (size_t)(bh * 64 + r0) * 4096 + ch0 * 16;
  const char* gV1 = (const char*)Vb + (size_t)(bh * 64 + r1) * 4096 + ch1 * 16;
  const float* bias_base = bias + (size_t)(bh * 2048 + q0 + w * 16 + quad * 4) * 2048 + c;
  const unsigned pb = w * 2048u;

  async_cp16((const char*)Qb + (size_t)(bh * 2048 + q0 + r0) * 128 + ch0 * 16, Qs + b0 * 16);
  async_cp16((const char*)Qb + (size_t)(bh * 2048 + q0 + r1) * 128 + ch1 * 16, Qs + b1 * 16);
  async_cp16(gK0, Ks0 + b0 * 16);
  async_cp16(gK1, Ks0 + b1 * 16);
  async_cp16(gV0, Vs0 + b0 * 16);
  async_cp16(gV1, Vs0 + b1 * 16);
  float bvA[4][4], bvB[4][4];
#pragma unroll
  for (int tt = 0; tt < 4; ++tt)
#pragma unroll
    for (int r = 0; r < 4; ++r)
      bvA[tt][r] = bias_base[(size_t)r * 2048 + tt * 16];
  __syncthreads();

  short8 aq[2];
  {
    unsigned row = w * 16 + c;
    aq[0] = *(const short8*)(Qs + row * 128 + 16 * ((quad + 0u) ^ (row & 7u)));
    aq[1] = *(const short8*)(Qs + row * 128 + 16 * ((quad + 4u) ^ (row & 7u)));
  }

  float mrun[4] = {-1e30f, -1e30f, -1e30f, -1e30f};
  float lrun[4] = {0.f, 0.f, 0.f, 0.f};
  floatx4 oacc[4] = {};

  for (unsigned tix = 0; tix < 32; ++tix) {
    const unsigned k0 = tix * 64u;
    const char* Kc = (tix & 1u) ? Ks1 : Ks0;
    const char* Vc = (tix & 1u) ? Vs1 : Vs0;

    if (tix + 1 < 32) {
      char* Kn = (tix & 1u) ? Ks0 : Ks1;
      char* Vn = (tix & 1u) ? Vs0 : Vs1;
      async_cp16(gK0 + (size_t)(k0 + 64) * 128, Kn + b0 * 16);
      async_cp16(gK1 + (size_t)(k0 + 64) * 128, Kn + b1 * 16);
      async_cp16(gV0 + (size_t)(k0 + 64) * 2, Vn + b0 * 16);
      async_cp16(gV1 + (size_t)(k0 + 64) * 2, Vn + b1 * 16);
#pragma unroll
      for (int tt = 0; tt < 4; ++tt)
#pragma unroll
        for (int r = 0; r < 4; ++r)
          bvB[tt][r] = bias_base[(size_t)r * 2048 + (k0 + 64) + tt * 16];
    }

    floatx4 s4[4] = {};
    __builtin_amdgcn_s_setprio(1);
#pragma unroll
    for (int ds = 0; ds < 2; ++ds)
#pragma unroll
      for (int tt = 0; tt < 4; ++tt) {
        unsigned row = tt * 16 + c;
        short8 kf = *(const short8*)(Kc + row * 128 + 16 * (((unsigned)quad + 4u * ds) ^ (c & 7u)));
        s4[tt] = __builtin_amdgcn_mfma_f32_16x16x32_bf16(aq[ds], kf, s4[tt], 0, 0, 0);
      }
    __builtin_amdgcn_s_setprio(0);

    float alpha[4];
    float pr[4][4];
#pragma unroll
    for (int r = 0; r < 4; ++r) {
      float x0 = fmaf(bvA[0][r], 8.0f, s4[0][r]) * (LOG2E / 8.0f);
      float x1 = fmaf(bvA[1][r], 8.0f, s4[1][r]) * (LOG2E / 8.0f);
      float x2 = fmaf(bvA[2][r], 8.0f, s4[2][r]) * (LOG2E / 8.0f);
      float x3 = fmaf(bvA[3][r], 8.0f, s4[3][r]) * (LOG2E / 8.0f);
      float mx = fmaxf(fmaxf(x0, x1), fmaxf(x2, x3));
      mx = fmaxf(mx, __shfl_xor(mx, 1));
      mx = fmaxf(mx, __shfl_xor(mx, 2));
      mx = fmaxf(mx, __shfl_xor(mx, 4));
      mx = fmaxf(mx, __shfl_xor(mx, 8));
      float mn = fmaxf(mrun[r], mx);
      float a = __builtin_amdgcn_exp2f(mrun[r] - mn);
      mrun[r] = mn;
      float p0 = __builtin_amdgcn_exp2f(x0 - mn);
      float p1 = __builtin_amdgcn_exp2f(x1 - mn);
      float p2 = __builtin_amdgcn_exp2f(x2 - mn);
      float p3 = __builtin_amdgcn_exp2f(x3 - mn);
      pr[0][r] = p0; pr[1][r] = p1; pr[2][r] = p2; pr[3][r] = p3;
      float rs = (p0 + p1) + (p2 + p3);
      rs += __shfl_xor(rs, 1);
      rs += __shfl_xor(rs, 2);
      rs += __shfl_xor(rs, 4);
      rs += __shfl_xor(rs, 8);
      lrun[r] = lrun[r] * a + rs;
      alpha[r] = a;
    }
#pragma unroll
    for (int dt = 0; dt < 4; ++dt) {
      oacc[dt][0] *= alpha[0]; oacc[dt][1] *= alpha[1];
      oacc[dt][2] *= alpha[2]; oacc[dt][3] *= alpha[3];
    }

#pragma unroll
    for (int tt = 0; tt < 4; ++tt)
#pragma unroll
      for (int r = 0; r < 4; ++r) {
        unsigned qq = quad * 4 + r;
        unsigned off = pb + qq * 128 + 16 * (((unsigned)(2 * tt) + (c >> 3)) ^ (qq & 7u)) + 2 * (c & 7u);
        *(u16*)(Ps + off) = f2bf(pr[tt][r]);
      }
    asm volatile("s_waitcnt lgkmcnt(0)" ::: "memory");

    __builtin_amdgcn_s_setprio(1);
#pragma unroll
    for (int js = 0; js < 2; ++js) {
      short8 pf = *(const short8*)(Ps + pb + (l & 15) * 128 +
                                   16 * (((unsigned)quad + 4u * js) ^ ((l & 15) & 7u)));
#pragma unroll
      for (int dt = 0; dt < 4; ++dt) {
        unsigned row = dt * 16 + c;
        short8 vf = *(const short8*)(Vc + row * 128 + 16 * (((unsigned)quad + 4u * js) ^ (c & 7u)));
        oacc[dt] = __builtin_amdgcn_mfma_f32_16x16x32_bf16(pf, vf, oacc[dt], 0, 0, 0);
      }
    }
    __builtin_amdgcn_s_setprio(0);

    __syncthreads();

    if (tix + 1 < 32) {
#pragma unroll
      for (int tt = 0; tt < 4; ++tt)
#pragma unroll
        for (int r = 0; r < 4; ++r)
          bvA[tt][r] = bvB[tt][r];
    }
  }

  unsigned b_ = bh / 12u, h = bh % 12u;
#pragma unroll
  for (int r = 0; r < 4; ++r) {
    float li = 1.0f / lrun[r];
    unsigned qg = q0 + w * 16 + quad * 4 + r;
    float* op = out + (size_t)(b_ * 2048 + qg) * 768 + h * 64 + c;
#pragma unroll
    for (int dt = 0; dt < 4; ++dt) op[dt * 16] = oacc[dt][r] * li;
  }
}

// ------------------------------- launch ------------------------------------
extern "C" void kernel_launch(void* const* d_in, const int* in_sizes, int n_in,
                              void* d_out, int out_size, void* d_ws, size_t ws_size,
                              hipStream_t stream) {
  const float* hidden = (const float*)d_in[0];   // 4096 x 768
  const float* Wqkv_w = (const float*)d_in[1];   // 2304 x 768
  const float* Wqkv_b = (const float*)d_in[2];   // 2304
  const float* bias   = (const float*)d_in[3];   // 2 x 12 x 2048 x 2048
  float* out = (float*)d_out;

  char* ws = (char*)d_ws;
  u16* Abf = (u16*)(ws);                 //  6,291,456 B
  u16* Wbf = (u16*)(ws + 6291456);       //  3,538,944 B
  u16* Qb  = (u16*)(ws + 9830400);       //  6,291,456 B
  u16* Kb  = (u16*)(ws + 16121856);      //  6,291,456 B
  u16* Vb  = (u16*)(ws + 22413312);      //  6,291,456 B  (total ~27.4 MB)

  pack_kernel<<<4800, 256, 0, stream>>>(hidden, Wqkv_w, Abf, Wbf);
  qkv_gemm<<<dim3(18, 32), 256, 0, stream>>>(Abf, Wbf, Wqkv_b, Qb, Kb, Vb);
  attn_kernel<<<3072, 256, 0, stream>>>(Qb, Kb, Vb, bias, out);
}

// Round 4
// 645.606 us; speedup vs baseline: 1.3575x; 1.3575x over previous
//
#include <hip/hip_runtime.h>

// ---------------------------------------------------------------------------
// BertAlibiUnpadSelfAttention on MI355X.
// K1 pack:  fp32 -> bf16 (hidden, Wqkv)                        [unchanged]
// K2 gemm:  qkv = hidden @ W^T + b, scatter Q,K,V^T bf16       [unchanged]
// K3 attn:  SPLIT-K flash attention. 3072 blocks = 24 bh x 32 qtiles x
//           4 k-splits (512 keys each, KVBLK=32, 16 steps). LDS 20 KB
//           (K/V dbuf 4KB tiles + 4KB P; Q direct to regs) ->
//           ~6 blocks/CU resident = 24 waves/CU (was 12).
//           Partials (unnorm O, m, l in base-2 domain) to workspace.
// K4 combine: merge 4 splits per q-row, write d_out.
// Rationale (R3 counters): attn was latency-bound (HBM 25%, Mfma 10%,
// VALU 40%, Occ 32%) with parallelism structurally capped at 12 waves/CU.
// ---------------------------------------------------------------------------

typedef __attribute__((ext_vector_type(8))) short short8;
typedef __attribute__((ext_vector_type(4))) float floatx4;
typedef unsigned short u16;
typedef unsigned int u32;

#define LOG2E 1.4426950408889634f

__device__ __forceinline__ u16 f2bf(float f) {
  u32 u = __float_as_uint(f);
  u += 0x7FFFu + ((u >> 16) & 1u);   // round-to-nearest-even
  return (u16)(u >> 16);
}

typedef const __attribute__((address_space(1))) u32* gp_t;
typedef __attribute__((address_space(3))) u32* lp_t;
__device__ __forceinline__ void async_cp16(const void* g, void* l) {
  __builtin_amdgcn_global_load_lds((gp_t)g, (lp_t)l, 16, 0, 0);
}

// ------------------------------- K1: pack ----------------------------------
__global__ __launch_bounds__(256) void pack_kernel(
    const float* __restrict__ A, const float* __restrict__ W,
    u16* __restrict__ Abf, u16* __restrict__ Wbf) {
  unsigned u = blockIdx.x * 256u + threadIdx.x;  // 1,228,800 float4 units
  const unsigned nA = 786432u;                   // 4096*768/4
  float4 v;
  u16* dst;
  if (u < nA) { v = ((const float4*)A)[u]; dst = Abf + u * 4; }
  else        { unsigned q = u - nA; v = ((const float4*)W)[q]; dst = Wbf + q * 4; }
  ushort4 o;
  o.x = f2bf(v.x); o.y = f2bf(v.y); o.z = f2bf(v.z); o.w = f2bf(v.w);
  *(ushort4*)dst = o;
}

// ------------------------------- K2: qkv gemm ------------------------------
// C[m,n] = sum_k Abf[m,k]*Wbf[n,k] + bq[n];  M=4096 N=2304 K=768
__global__ __launch_bounds__(256, 3) void qkv_gemm(
    const u16* __restrict__ Abf, const u16* __restrict__ Wbf,
    const float* __restrict__ bq,
    u16* __restrict__ Qb, u16* __restrict__ Kb, u16* __restrict__ Vb) {
  __shared__ __align__(16) char smem[32768];
  char* As0 = smem;
  char* Bs0 = smem + 8192;
  char* As1 = smem + 16384;
  char* Bs1 = smem + 24576;
  const unsigned t = threadIdx.x;
  unsigned orig = blockIdx.y * 18u + blockIdx.x;
  unsigned wg = (orig & 7u) * 72u + (orig >> 3);
  const unsigned nblk = wg % 18u, mblk = wg / 18u;
  const unsigned w = t >> 6, l = t & 63, quad = l >> 4, c = l & 15;
  const unsigned wm = (w >> 1) * 64, wn = (w & 1) * 64;

  floatx4 acc[4][4] = {};

  const unsigned b0 = t, b1 = t + 256u;
  const unsigned r0 = b0 >> 2, ch0 = (b0 & 3u) ^ (r0 & 3u);
  const unsigned r1 = b1 >> 2, ch1 = (b1 & 3u) ^ (r1 & 3u);
  const char* gA0 = (const char*)Abf + (size_t)((mblk * 128 + r0) * 768) * 2 + ch0 * 16;
  const char* gA1 = (const char*)Abf + (size_t)((mblk * 128 + r1) * 768) * 2 + ch1 * 16;
  const char* gB0 = (const char*)Wbf + (size_t)((nblk * 128 + r0) * 768) * 2 + ch0 * 16;
  const char* gB1 = (const char*)Wbf + (size_t)((nblk * 128 + r1) * 768) * 2 + ch1 * 16;

  async_cp16(gA0, As0 + b0 * 16);
  async_cp16(gA1, As0 + b1 * 16);
  async_cp16(gB0, Bs0 + b0 * 16);
  async_cp16(gB1, Bs0 + b1 * 16);
  __syncthreads();

  for (unsigned kt = 0; kt < 24; ++kt) {
    char* Ac = (kt & 1u) ? As1 : As0;
    char* Bc = (kt & 1u) ? Bs1 : Bs0;
    if (kt + 1 < 24) {
      char* An = (kt & 1u) ? As0 : As1;
      char* Bn = (kt & 1u) ? Bs0 : Bs1;
      async_cp16(gA0 + (kt + 1) * 64, An + b0 * 16);
      async_cp16(gA1 + (kt + 1) * 64, An + b1 * 16);
      async_cp16(gB0 + (kt + 1) * 64, Bn + b0 * 16);
      async_cp16(gB1 + (kt + 1) * 64, Bn + b1 * 16);
    }
    short8 af[4], bf[4];
#pragma unroll
    for (int mt = 0; mt < 4; ++mt) {
      unsigned row = wm + mt * 16 + c;
      af[mt] = *(const short8*)(Ac + row * 64 + 16 * (quad ^ (row & 3u)));
    }
#pragma unroll
    for (int nt = 0; nt < 4; ++nt) {
      unsigned row = wn + nt * 16 + c;
      bf[nt] = *(const short8*)(Bc + row * 64 + 16 * (quad ^ (row & 3u)));
    }
#pragma unroll
    for (int mt = 0; mt < 4; ++mt)
#pragma unroll
      for (int nt = 0; nt < 4; ++nt)
        acc[mt][nt] = __builtin_amdgcn_mfma_f32_16x16x32_bf16(af[mt], bf[nt], acc[mt][nt], 0, 0, 0);
    __syncthreads();
  }

  float bqv[4];
#pragma unroll
  for (int nt = 0; nt < 4; ++nt) bqv[nt] = bq[nblk * 128 + wn + nt * 16 + c];
#pragma unroll
  for (int mt = 0; mt < 4; ++mt) {
#pragma unroll
    for (int r = 0; r < 4; ++r) {
      unsigned m = mblk * 128 + wm + mt * 16 + quad * 4 + r;
      unsigned bb = m >> 11, s = m & 2047u;
#pragma unroll
      for (int nt = 0; nt < 4; ++nt) {
        float val = acc[mt][nt][r] + bqv[nt];
        unsigned n = nblk * 128 + wn + nt * 16 + c;
        u16 bv = f2bf(val);
        if (n < 768u) {
          unsigned h = n >> 6, d = n & 63u;
          Qb[(((bb * 12 + h) * 2048 + s) << 6) + d] = bv;
        } else if (n < 1536u) {
          unsigned n2 = n - 768u, h = n2 >> 6, d = n2 & 63u;
          Kb[(((bb * 12 + h) * 2048 + s) << 6) + d] = bv;
        } else {
          unsigned n2 = n - 1536u, h = n2 >> 6, d = n2 & 63u;
          Vb[(((bb * 12 + h) << 6) + d) * 2048 + s] = bv;
        }
      }
    }
  }
}

// ------------------------------- K3: split-K attention ---------------------
// grid 3072 = 24 bh x 32 qtiles x 4 splits. Each block: 64 q-rows, keys
// [sp*512, sp*512+512), KVBLK=32 (16 steps). LDS 20 KB. Partials out.
__global__ __launch_bounds__(256, 6) void attn_kernel(
    const u16* __restrict__ Qb, const u16* __restrict__ Kb,
    const u16* __restrict__ Vb, const float* __restrict__ bias,
    float* __restrict__ Op, float* __restrict__ Mp, float* __restrict__ Lp) {
  __shared__ __align__(16) char smem[20480];
  char* Ks0 = smem;            // 4KB: 32 keys x 128B
  char* Ks1 = smem + 4096;
  char* Vs0 = smem + 8192;     // 4KB: 64 d-rows x 64B (V^T k-slice)
  char* Vs1 = smem + 12288;
  char* Ps  = smem + 16384;    // 4KB: 4 waves x (16 q x 64B)
  const unsigned t = threadIdx.x;
  // XCD-chunked swizzle (3072 % 8 == 0, bijective): 384 blocks/XCD = 3 bh
  unsigned wgid = (blockIdx.x & 7u) * 384u + (blockIdx.x >> 3);
  const unsigned bh = wgid >> 7;          // /128
  const unsigned rem = wgid & 127u;
  const unsigned qt = rem >> 2, sp = rem & 3u;
  const unsigned q0 = qt * 64;
  const unsigned w = t >> 6, l = t & 63, quad = l >> 4, c = l & 15;

  // staging decomposition: K tile 256 chunks (32 rows x 8), V tile 256 (64 x 4)
  const unsigned rK = t >> 3, chK = (t & 7u) ^ (rK & 7u);
  const unsigned rV = t >> 2, chV = (t & 3u) ^ (rV & 3u);

  const char* gK = (const char*)Kb + (size_t)(bh * 2048 + sp * 512 + rK) * 128 + chK * 16;
  const char* gV = (const char*)Vb + (size_t)(bh * 64 + rV) * 4096 + sp * 1024 + chV * 16;
  const float* bias_base = bias + (size_t)(bh * 2048 + q0 + w * 16 + quad * 4) * 2048
                                + sp * 512 + c;
  const unsigned pb = w * 1024u;  // this wave's P region (16 q x 64B)

  // prologue: stage K/V tile 0; Q fragment straight to registers; bias tile 0
  async_cp16(gK, Ks0 + t * 16);
  async_cp16(gV, Vs0 + t * 16);
  short8 aq[2];
  {
    const u16* qrow = Qb + (size_t)(bh * 2048 + q0 + w * 16 + c) * 64 + quad * 8;
    aq[0] = *(const short8*)(qrow);        // d =  quad*8 .. +7
    aq[1] = *(const short8*)(qrow + 32);   // d = 32+quad*8 .. +7
  }
  float bvA[2][4], bvB[2][4];
#pragma unroll
  for (int tt = 0; tt < 2; ++tt)
#pragma unroll
    for (int r = 0; r < 4; ++r)
      bvA[tt][r] = bias_base[(size_t)r * 2048 + tt * 16];
  __syncthreads();

  float mrun[4] = {-1e30f, -1e30f, -1e30f, -1e30f};
  float lrun[4] = {0.f, 0.f, 0.f, 0.f};
  floatx4 oacc[4] = {};

  for (unsigned i = 0; i < 16; ++i) {
    const char* Kc = (i & 1u) ? Ks1 : Ks0;
    const char* Vc = (i & 1u) ? Vs1 : Vs0;

    if (i + 1 < 16) {
      char* Kn = (i & 1u) ? Ks0 : Ks1;
      char* Vn = (i & 1u) ? Vs0 : Vs1;
      async_cp16(gK + (size_t)(i + 1) * 4096, Kn + t * 16);
      async_cp16(gV + (size_t)(i + 1) * 64, Vn + t * 16);
#pragma unroll
      for (int tt = 0; tt < 2; ++tt)
#pragma unroll
        for (int r = 0; r < 4; ++r)
          bvB[tt][r] = bias_base[(size_t)r * 2048 + (i + 1) * 32 + tt * 16];
    }

    // S = Q K^T  (16 q x 32 keys)
    floatx4 s4[2] = {};
    __builtin_amdgcn_s_setprio(1);
#pragma unroll
    for (int ds = 0; ds < 2; ++ds)
#pragma unroll
      for (int tt = 0; tt < 2; ++tt) {
        unsigned row = tt * 16 + c;  // key
        short8 kf = *(const short8*)(Kc + row * 128 + 16 * (((unsigned)quad + 4u * ds) ^ (c & 7u)));
        s4[tt] = __builtin_amdgcn_mfma_f32_16x16x32_bf16(aq[ds], kf, s4[tt], 0, 0, 0);
      }
    __builtin_amdgcn_s_setprio(0);

    // online softmax (base-2): x = (dot + 8*bias) * log2e/8
    float alpha[4];
    float pr[2][4];
#pragma unroll
    for (int r = 0; r < 4; ++r) {
      float x0 = fmaf(bvA[0][r], 8.0f, s4[0][r]) * (LOG2E / 8.0f);
      float x1 = fmaf(bvA[1][r], 8.0f, s4[1][r]) * (LOG2E / 8.0f);
      float mx = fmaxf(x0, x1);
      mx = fmaxf(mx, __shfl_xor(mx, 1));
      mx = fmaxf(mx, __shfl_xor(mx, 2));
      mx = fmaxf(mx, __shfl_xor(mx, 4));
      mx = fmaxf(mx, __shfl_xor(mx, 8));
      float mn = fmaxf(mrun[r], mx);
      float a = __builtin_amdgcn_exp2f(mrun[r] - mn);
      mrun[r] = mn;
      float p0 = __builtin_amdgcn_exp2f(x0 - mn);
      float p1 = __builtin_amdgcn_exp2f(x1 - mn);
      pr[0][r] = p0; pr[1][r] = p1;
      float rs = p0 + p1;
      rs += __shfl_xor(rs, 1);
      rs += __shfl_xor(rs, 2);
      rs += __shfl_xor(rs, 4);
      rs += __shfl_xor(rs, 8);
      lrun[r] = lrun[r] * a + rs;
      alpha[r] = a;
    }
#pragma unroll
    for (int dt = 0; dt < 4; ++dt) {
      oacc[dt][0] *= alpha[0]; oacc[dt][1] *= alpha[1];
      oacc[dt][2] *= alpha[2]; oacc[dt][3] *= alpha[3];
    }

    // P (C-layout: key=c+16tt, q=quad*4+r) -> LDS A-operand layout, wave-private
#pragma unroll
    for (int tt = 0; tt < 2; ++tt)
#pragma unroll
      for (int r = 0; r < 4; ++r) {
        unsigned qq = quad * 4 + r;
        unsigned off = pb + qq * 64 + 16 * (((unsigned)(2 * tt) + (c >> 3)) ^ (qq & 3u)) + 2 * (c & 7u);
        *(u16*)(Ps + off) = f2bf(pr[tt][r]);
      }
    asm volatile("s_waitcnt lgkmcnt(0)" ::: "memory");

    // O += P V  (K-dim = 32 keys = one MFMA per dt)
    __builtin_amdgcn_s_setprio(1);
    {
      short8 pf = *(const short8*)(Ps + pb + (l & 15) * 64 + 16 * ((unsigned)quad ^ ((l & 15) & 3u)));
#pragma unroll
      for (int dt = 0; dt < 4; ++dt) {
        unsigned row = dt * 16 + c;  // V^T row = d
        short8 vf = *(const short8*)(Vc + row * 64 + 16 * ((unsigned)quad ^ (c & 3u)));
        oacc[dt] = __builtin_amdgcn_mfma_f32_16x16x32_bf16(pf, vf, oacc[dt], 0, 0, 0);
      }
    }
    __builtin_amdgcn_s_setprio(0);

    __syncthreads();  // drains prefetch (vmcnt); next buffer ready; cur reusable

    if (i + 1 < 16) {
#pragma unroll
      for (int tt = 0; tt < 2; ++tt)
#pragma unroll
        for (int r = 0; r < 4; ++r)
          bvA[tt][r] = bvB[tt][r];
    }
  }

  // epilogue: unnormalized partials (base-2 m, l)
  const unsigned pidx = (bh * 32u + qt) * 4u + sp;
#pragma unroll
  for (int r = 0; r < 4; ++r) {
    unsigned row = w * 16 + quad * 4 + r;
    float* op = Op + (size_t)pidx * 4096 + row * 64 + c;
#pragma unroll
    for (int dt = 0; dt < 4; ++dt) op[dt * 16] = oacc[dt][r];
    if (c == 0) {
      Mp[pidx * 64 + row] = mrun[r];
      Lp[pidx * 64 + row] = lrun[r];
    }
  }
}

// ------------------------------- K4: combine -------------------------------
// out[(b*2048+q)*768 + h*64 + d] = sum_sp(O_sp * 2^(m_sp-m*)) / sum_sp(l_sp * 2^(m_sp-m*))
__global__ __launch_bounds__(256) void combine_kernel(
    const float* __restrict__ Op, const float* __restrict__ Mp,
    const float* __restrict__ Lp, float* __restrict__ out) {
  unsigned gid = blockIdx.x * 256u + threadIdx.x;  // 3,145,728 = 24*2048*64
  unsigned d = gid & 63u;
  unsigned row = gid >> 6;          // bh*2048 + q
  unsigned bh = row >> 11, q = row & 2047u;
  unsigned qt = q >> 6, qr = q & 63u;
  unsigned pidx0 = (bh * 32u + qt) * 4u;
  size_t ob = (size_t)pidx0 * 4096 + qr * 64u + d;
  unsigned mb = pidx0 * 64u + qr;
  float m0 = Mp[mb], m1 = Mp[mb + 64], m2 = Mp[mb + 128], m3 = Mp[mb + 192];
  float ms = fmaxf(fmaxf(m0, m1), fmaxf(m2, m3));
  float w0 = __builtin_amdgcn_exp2f(m0 - ms);
  float w1 = __builtin_amdgcn_exp2f(m1 - ms);
  float w2 = __builtin_amdgcn_exp2f(m2 - ms);
  float w3 = __builtin_amdgcn_exp2f(m3 - ms);
  float den = w0 * Lp[mb] + w1 * Lp[mb + 64] + w2 * Lp[mb + 128] + w3 * Lp[mb + 192];
  float num = w0 * Op[ob] + w1 * Op[ob + 4096] + w2 * Op[ob + 8192] + w3 * Op[ob + 12288];
  unsigned b_ = bh / 12u, h = bh - b_ * 12u;
  out[(size_t)(b_ * 2048 + q) * 768 + h * 64 + d] = num / den;
}

// ------------------------------- launch ------------------------------------
extern "C" void kernel_launch(void* const* d_in, const int* in_sizes, int n_in,
                              void* d_out, int out_size, void* d_ws, size_t ws_size,
                              hipStream_t stream) {
  const float* hidden = (const float*)d_in[0];   // 4096 x 768
  const float* Wqkv_w = (const float*)d_in[1];   // 2304 x 768
  const float* Wqkv_b = (const float*)d_in[2];   // 2304
  const float* bias   = (const float*)d_in[3];   // 2 x 12 x 2048 x 2048
  float* out = (float*)d_out;

  char* ws = (char*)d_ws;
  u16* Abf = (u16*)(ws);                 //  6,291,456 B
  u16* Wbf = (u16*)(ws + 6291456);       //  3,538,944 B
  u16* Qb  = (u16*)(ws + 9830400);       //  6,291,456 B
  u16* Kb  = (u16*)(ws + 16121856);      //  6,291,456 B
  u16* Vb  = (u16*)(ws + 22413312);      //  6,291,456 B
  float* Op = (float*)(ws + 28704768);   // 50,331,648 B (3072 x 64 x 64 f32)
  float* Mp = (float*)(ws + 79036416);   //    786,432 B
  float* Lp = (float*)(ws + 79822848);   //    786,432 B  (total ~80.6 MB)

  pack_kernel<<<4800, 256, 0, stream>>>(hidden, Wqkv_w, Abf, Wbf);
  qkv_gemm<<<dim3(18, 32), 256, 0, stream>>>(Abf, Wbf, Wqkv_b, Qb, Kb, Vb);
  attn_kernel<<<3072, 256, 0, stream>>>(Qb, Kb, Vb, bias, Op, Mp, Lp);
  combine_kernel<<<12288, 256, 0, stream>>>(Op, Mp, Lp, out);
}